// Round 11
// baseline (93.045 us; speedup 1.0000x reference)
//
#include <hip/hip_runtime.h>
#include <hip/hip_bf16.h>
#include <math.h>

#define C_DIM 384
#define NHEADS 6
#define HD 64
#define BATCH 8
#define NSEQ 1024
#define M_ROWS (BATCH * NSEQ)
#define BLDP 392   // padded B row in LDS (bf16): 784B stride -> ~2-way banks

typedef __attribute__((ext_vector_type(4))) float f32x4;
typedef __attribute__((ext_vector_type(8))) short s16x8;

__device__ __forceinline__ float bf2f(short u) {
  return __uint_as_float(((unsigned)(unsigned short)u) << 16);
}
__device__ __forceinline__ short f2bf(float f) {
  __hip_bfloat16 h = __float2bfloat16(f);
  return *reinterpret_cast<short*>(&h);
}
__device__ __forceinline__ s16x8 cvt8(float4 a, float4 b) {
  s16x8 r;
  r[0] = f2bf(a.x); r[1] = f2bf(a.y); r[2] = f2bf(a.z); r[3] = f2bf(a.w);
  r[4] = f2bf(b.x); r[5] = f2bf(b.y); r[6] = f2bf(b.z); r[7] = f2bf(b.w);
  return r;
}

__device__ __forceinline__ void gload_lds16(const void* g, void* l) {
  __builtin_amdgcn_global_load_lds(
      (const __attribute__((address_space(1))) unsigned int*)g,
      (__attribute__((address_space(3))) unsigned int*)l, 16, 0, 0);
}

// ---------------------------------------------------------------------------
// B-stationary GEMM: out[M,N] = A[M,K] @ W[N,K]^T (+bias).
// BM=128, BN=64, 256 threads = 4 waves (2x2; wave tile 64x32).
// Whole B column-panel [64][K] cast fp32->bf16 into LDS ONCE (only barrier).
// K-loop pure per-wave: A direct global->reg (cvt for fp32 A), B from
// read-only padded LDS, MFMA. No K-loop barriers; 3 blocks/CU TLP.
// ---------------------------------------------------------------------------
template<bool A_BF16, bool OUT_BF16>
__global__ __launch_bounds__(256) void gemm_bstat(
    const void* __restrict__ Ap, const float* __restrict__ W,
    const float* __restrict__ bias, void* __restrict__ outp,
    int M, int N, int K) {
  __shared__ __align__(16) __hip_bfloat16 Bs[64 * BLDP];

  const int tid = threadIdx.x;
  const int nwg = gridDim.x * gridDim.y;           // 1152 / 384, %8==0
  const int bid0 = blockIdx.y * gridDim.x + blockIdx.x;
  const int cpx = nwg >> 3;
  const int wg = (bid0 & 7) * cpx + (bid0 >> 3);   // bijective XCD swizzle
  const int bx = wg % gridDim.x;
  const int by = wg / gridDim.x;

  const int lane = tid & 63;
  const int wave = tid >> 6;        // 0..3
  const int wr = (wave >> 1) * 64;  // 0,64
  const int wc = (wave & 1) * 32;   // 0,32
  const int rowBase = by * 128;
  const int colBase = bx * 64;
  const int l16 = lane & 15;
  const int lk8 = (lane >> 4) * 8;
  const int lr4 = (lane >> 4) * 4;

  // ---- prologue: stage whole B tile [64][384] fp32 -> bf16 LDS ----
#pragma unroll
  for (int i = 0; i < 6; ++i) {
    int c = tid + i * 256;          // 0..1535 chunks of 16 fp32
    int row = c / 24;               // 24 chunks per row (384/16)
    int col = (c % 24) * 16;
    const float4* src = (const float4*)(W + (size_t)(colBase + row) * K + col);
    float4 u0 = src[0], u1 = src[1], u2 = src[2], u3 = src[3];
    *(s16x8*)&Bs[row * BLDP + col]     = cvt8(u0, u1);
    *(s16x8*)&Bs[row * BLDP + col + 8] = cvt8(u2, u3);
  }
  __syncthreads();

  f32x4 acc[4][2] = {};
  const int nkt = K >> 5;  // 12

#pragma unroll 2
  for (int kt = 0; kt < nkt; ++kt) {
    s16x8 af[4], bfr[2];
#pragma unroll
    for (int m = 0; m < 4; ++m) {
      size_t rowOff = (size_t)(rowBase + wr + m * 16 + l16) * K + kt * 32 + lk8;
      if constexpr (A_BF16) {
        af[m] = *(const s16x8*)((const __hip_bfloat16*)Ap + rowOff);
      } else {
        const float4* ap = (const float4*)((const float*)Ap + rowOff);
        af[m] = cvt8(ap[0], ap[1]);
      }
    }
#pragma unroll
    for (int n = 0; n < 2; ++n)
      bfr[n] = *(const s16x8*)(&Bs[(wc + n * 16 + l16) * BLDP + kt * 32 + lk8]);
#pragma unroll
    for (int m = 0; m < 4; ++m)
#pragma unroll
      for (int n = 0; n < 2; ++n)
        acc[m][n] = __builtin_amdgcn_mfma_f32_16x16x32_bf16(
            af[m], bfr[n], acc[m][n], 0, 0, 0);
  }

#pragma unroll
  for (int m = 0; m < 4; ++m) {
    int rb = rowBase + wr + m * 16 + lr4;
#pragma unroll
    for (int n = 0; n < 2; ++n) {
      int cb = colBase + wc + n * 16 + l16;
      float bv = OUT_BF16 ? 0.f : bias[cb];
#pragma unroll
      for (int j = 0; j < 4; ++j) {
        if constexpr (OUT_BF16) {
          ((__hip_bfloat16*)outp)[(size_t)(rb + j) * N + cb] =
              __float2bfloat16(acc[m][n][j]);
        } else {
          ((float*)outp)[(size_t)(rb + j) * N + cb] = acc[m][n][j] + bv;
        }
      }
    }
  }
}

// ---------------------------------------------------------------------------
// Local attention: one block per (128-row panel, head). LDS-staged q/k/v with
// XOR-pre-swizzled global source (linear LDS dest), 2 threads per row.
// (unchanged)
// ---------------------------------------------------------------------------
__global__ __launch_bounds__(256) void local_attn_v3(
    const __hip_bfloat16* __restrict__ qkv, __hip_bfloat16* __restrict__ attn_out) {
  __shared__ __align__(16) ushort lds[24832];
  const int QOFF = 0;
  const int KOFF = 8192;
  const int VOFF = 8192 + 8320;

  const int tid = threadIdx.x;
  const int mb = blockIdx.x & 63;
  const int h  = blockIdx.x >> 6;
  const int rb = mb * 128;
  const int b  = rb >> 10;
  const int n0 = rb & 1023;
  const int RS = 3 * C_DIM;

#pragma unroll
  for (int i = 0; i < 4; ++i) {
    int s = i * 256 + tid;
    int r = s >> 3;
    int jg = (s & 7) ^ (r & 7);
    gload_lds16(qkv + (size_t)(rb + r) * RS + h * HD + jg * 8,
                lds + QOFF + s * 8);
  }
#pragma unroll
  for (int i = 0; i < 5; ++i) {
    int s = i * 256 + tid;
    if (s < 1040) {
      int r = s >> 3;
      int jg = (s & 7) ^ (r & 7);
      int nl = n0 + r - 1;
      nl = nl < 0 ? 0 : (nl > 1023 ? 1023 : nl);
      size_t row = (size_t)(b << 10) + nl;
      gload_lds16(qkv + row * RS + C_DIM + h * HD + jg * 8, lds + KOFF + s * 8);
      gload_lds16(qkv + row * RS + 2 * C_DIM + h * HD + jg * 8, lds + VOFF + s * 8);
    }
  }
  __syncthreads();

  const int r = tid >> 1;
  const int half = tid & 1;
  const int jbase = half * 4;
  const int n = n0 + r;

  float qf[32];
#pragma unroll
  for (int c = 0; c < 4; ++c) {
    int slot = r * 8 + ((jbase + c) ^ (r & 7));
    s16x8 v = *(const s16x8*)(lds + QOFF + slot * 8);
#pragma unroll
    for (int e = 0; e < 8; ++e) qf[c * 8 + e] = bf2f(v[e]);
  }

  float s3[3];
#pragma unroll
  for (int jj = 0; jj < 3; ++jj) {
    int krow = r + jj;
    float acc = 0.f;
#pragma unroll
    for (int c = 0; c < 4; ++c) {
      int slot = krow * 8 + ((jbase + c) ^ (krow & 7));
      s16x8 v = *(const s16x8*)(lds + KOFF + slot * 8);
#pragma unroll
      for (int e = 0; e < 8; ++e) acc += qf[c * 8 + e] * bf2f(v[e]);
    }
    acc += __shfl_xor(acc, 1);
    s3[jj] = ((unsigned)(n + jj - 1) < (unsigned)NSEQ) ? acc * 0.125f : -1e30f;
  }

  float mx = fmaxf(s3[0], fmaxf(s3[1], s3[2]));
  float p0 = __expf(s3[0] - mx);
  float p1 = __expf(s3[1] - mx);
  float p2 = __expf(s3[2] - mx);
  float inv = 1.f / (p0 + p1 + p2);
  float p[3] = {p0 * inv, p1 * inv, p2 * inv};

  float of[32] = {};
#pragma unroll
  for (int jj = 0; jj < 3; ++jj) {
    int krow = r + jj;
    float pw = p[jj];
#pragma unroll
    for (int c = 0; c < 4; ++c) {
      int slot = krow * 8 + ((jbase + c) ^ (krow & 7));
      s16x8 v = *(const s16x8*)(lds + VOFF + slot * 8);
#pragma unroll
      for (int e = 0; e < 8; ++e) of[c * 8 + e] += pw * bf2f(v[e]);
    }
  }

#pragma unroll
  for (int c = 0; c < 4; ++c) {
    s16x8 o;
#pragma unroll
    for (int e = 0; e < 8; ++e) o[e] = f2bf(of[c * 8 + e]);
    *(s16x8*)(attn_out + (size_t)(rb + r) * C_DIM + h * HD + jbase * 8 + c * 8) = o;
  }
}

extern "C" void kernel_launch(void* const* d_in, const int* in_sizes, int n_in,
                              void* d_out, int out_size, void* d_ws, size_t ws_size,
                              hipStream_t stream) {
  const float* x      = (const float*)d_in[0];  // [B,N,C]
  const float* qkv_w  = (const float*)d_in[1];  // [3C,C]
  const float* proj_w = (const float*)d_in[2];  // [C,C]
  const float* proj_b = (const float*)d_in[3];  // [C]
  float* out = (float*)d_out;                   // [B,N,C] fp32

  __hip_bfloat16* qkv_bf  = (__hip_bfloat16*)d_ws;                 // [8192,1152]
  __hip_bfloat16* attn_bf = qkv_bf + (size_t)M_ROWS * 3 * C_DIM;   // [8192,384]

  // 1) qkv = x @ qkv_w^T (fused fp32->bf16 cast), 18x64 = 1152 blocks
  gemm_bstat<false, true><<<dim3(18, 64), 256, 0, stream>>>(
      x, qkv_w, nullptr, qkv_bf, M_ROWS, 3 * C_DIM, C_DIM);

  // 2) banded local attention (window 3): 64 row-panels x 6 heads
  local_attn_v3<<<64 * NHEADS, 256, 0, stream>>>(qkv_bf, attn_bf);

  // 3) out = attn @ proj_w^T + proj_b, 6x64 = 384 blocks
  gemm_bstat<true, false><<<dim3(6, 64), 256, 0, stream>>>(
      attn_bf, proj_w, proj_b, out, M_ROWS, C_DIM, C_DIM);
}

// Round 12
// 44.458 us; speedup vs baseline: 2.0929x; 2.0929x over previous
//
#include <hip/hip_runtime.h>
#include <hip/hip_bf16.h>
#include <math.h>

#define C_DIM 384
#define NHEADS 6
#define HD 64
#define BATCH 8
#define NSEQ 1024
#define M_ROWS (BATCH * NSEQ)
#define LDP 40   // padded LDS row (bf16): 80B stride -> ~2-way banks

typedef __attribute__((ext_vector_type(4))) float f32x4;
typedef __attribute__((ext_vector_type(8))) short s16x8;

__device__ __forceinline__ float bf2f(short u) {
  return __uint_as_float(((unsigned)(unsigned short)u) << 16);
}
__device__ __forceinline__ short f2bf(float f) {
  __hip_bfloat16 h = __float2bfloat16(f);
  return *reinterpret_cast<short*>(&h);
}
__device__ __forceinline__ s16x8 cvt8(float4 a, float4 b) {
  s16x8 r;
  r[0] = f2bf(a.x); r[1] = f2bf(a.y); r[2] = f2bf(a.z); r[3] = f2bf(a.w);
  r[4] = f2bf(b.x); r[5] = f2bf(b.y); r[6] = f2bf(b.z); r[7] = f2bf(b.w);
  return r;
}

__device__ __forceinline__ void gload_lds16(const void* g, void* l) {
  __builtin_amdgcn_global_load_lds(
      (const __attribute__((address_space(1))) unsigned int*)g,
      (__attribute__((address_space(3))) unsigned int*)l, 16, 0, 0);
}

__device__ __forceinline__ void wait_vm0() {
  asm volatile("s_waitcnt vmcnt(0)" ::: "memory");
}
__device__ __forceinline__ void lgkm0() {
  asm volatile("s_waitcnt lgkmcnt(0)" ::: "memory");
}
__device__ __forceinline__ void bar() {
  __builtin_amdgcn_sched_barrier(0);
  __builtin_amdgcn_s_barrier();
  __builtin_amdgcn_sched_barrier(0);
}

// ---------------------------------------------------------------------------
// Reg-staged GEMM: out[M,N] = A[M,K] @ W[N,K]^T (+bias).
// BM=128, BN=64, BK=32, 256 threads = 4 waves (2x2; wave tile 64x32).
// A (fp32 or bf16) and W (fp32) reg-staged -> cvt bf16 -> ds_write into
// padded double-buffered LDS. R6's exact 2-barrier loop; many small blocks
// (gemm1: 1152 = ~4.5/CU) so desynced blocks hide each other's stage drain.
// ---------------------------------------------------------------------------
template<bool A_BF16, bool OUT_BF16>
__global__ __launch_bounds__(256) void gemm_rs(
    const void* __restrict__ Ap, const float* __restrict__ W,
    const float* __restrict__ bias, void* __restrict__ outp,
    int M, int N, int K) {
  __shared__ __align__(16) __hip_bfloat16 As[2][128 * LDP];
  __shared__ __align__(16) __hip_bfloat16 Bs[2][64 * LDP];

  const int tid = threadIdx.x;
  const int nwg = gridDim.x * gridDim.y;           // 1152 / 384, %8==0
  const int bid0 = blockIdx.y * gridDim.x + blockIdx.x;
  const int cpx = nwg >> 3;
  const int wg = (bid0 & 7) * cpx + (bid0 >> 3);   // bijective XCD swizzle
  const int bx = wg % gridDim.x;
  const int by = wg / gridDim.x;

  const int lane = tid & 63;
  const int wave = tid >> 6;        // 0..3
  const int wr = (wave >> 1) * 64;  // 0,64
  const int wc = (wave & 1) * 32;   // 0,32
  const int rowBase = by * 128;
  const int colBase = bx * 64;
  const int l16 = lane & 15;
  const int lk8 = (lane >> 4) * 8;
  const int lr4 = (lane >> 4) * 4;

  // A staging: row srA (0..127), 16 K-elems at scA
  const int srA = tid >> 1;
  const int scA = (tid & 1) * 16;
  // B staging: row srB (0..63), 8 K-elems at scB
  const int srB = tid >> 2;
  const int scB = (tid & 3) * 8;
  const float* bSrc = W + (size_t)(colBase + srB) * K + scB;

  f32x4 acc[4][2] = {};
  float4 aF[4];        // fp32 A prefetch (16 floats)
  s16x8 aH[2];         // bf16 A prefetch (16 bf16)
  float4 bL[2];

  auto loadRegs = [&](int kt) {
    if constexpr (A_BF16) {
      const s16x8* ap = (const s16x8*)((const __hip_bfloat16*)Ap +
          (size_t)(rowBase + srA) * K + kt * 32 + scA);
      aH[0] = ap[0]; aH[1] = ap[1];
    } else {
      const float4* ap = (const float4*)((const float*)Ap +
          (size_t)(rowBase + srA) * K + kt * 32 + scA);
      aF[0] = ap[0]; aF[1] = ap[1]; aF[2] = ap[2]; aF[3] = ap[3];
    }
    const float4* bp = (const float4*)(bSrc + kt * 32);
    bL[0] = bp[0]; bL[1] = bp[1];
  };
  auto writeLds = [&](int buf) {
    if constexpr (A_BF16) {
      *(s16x8*)&As[buf][srA * LDP + scA]     = aH[0];
      *(s16x8*)&As[buf][srA * LDP + scA + 8] = aH[1];
    } else {
      *(s16x8*)&As[buf][srA * LDP + scA]     = cvt8(aF[0], aF[1]);
      *(s16x8*)&As[buf][srA * LDP + scA + 8] = cvt8(aF[2], aF[3]);
    }
    *(s16x8*)&Bs[buf][srB * LDP + scB] = cvt8(bL[0], bL[1]);
  };

  loadRegs(0);
  const int nkt = K >> 5;  // 12
  for (int kt = 0; kt < nkt; ++kt) {
    const int cur = kt & 1;
    wait_vm0();
    __builtin_amdgcn_sched_barrier(0);
    writeLds(cur);
    if (kt + 1 < nkt) loadRegs(kt + 1);  // in flight across barrier + MFMA
    lgkm0();
    bar();

    s16x8 af[4], bfr[2];
#pragma unroll
    for (int m = 0; m < 4; ++m)
      af[m] = *(const s16x8*)(&As[cur][(wr + m * 16 + l16) * LDP + lk8]);
#pragma unroll
    for (int n = 0; n < 2; ++n)
      bfr[n] = *(const s16x8*)(&Bs[cur][(wc + n * 16 + l16) * LDP + lk8]);
#pragma unroll
    for (int m = 0; m < 4; ++m)
#pragma unroll
      for (int n = 0; n < 2; ++n)
        acc[m][n] = __builtin_amdgcn_mfma_f32_16x16x32_bf16(
            af[m], bfr[n], acc[m][n], 0, 0, 0);
    bar();
  }

#pragma unroll
  for (int m = 0; m < 4; ++m) {
    int rb = rowBase + wr + m * 16 + lr4;
#pragma unroll
    for (int n = 0; n < 2; ++n) {
      int cb = colBase + wc + n * 16 + l16;
      float bv = OUT_BF16 ? 0.f : bias[cb];
#pragma unroll
      for (int j = 0; j < 4; ++j) {
        if constexpr (OUT_BF16) {
          ((__hip_bfloat16*)outp)[(size_t)(rb + j) * N + cb] =
              __float2bfloat16(acc[m][n][j]);
        } else {
          ((float*)outp)[(size_t)(rb + j) * N + cb] = acc[m][n][j] + bv;
        }
      }
    }
  }
}

// ---------------------------------------------------------------------------
// Local attention: one block per (128-row panel, head). LDS-staged q/k/v with
// XOR-pre-swizzled global source (linear LDS dest), 2 threads per row.
// (unchanged)
// ---------------------------------------------------------------------------
__global__ __launch_bounds__(256) void local_attn_v3(
    const __hip_bfloat16* __restrict__ qkv, __hip_bfloat16* __restrict__ attn_out) {
  __shared__ __align__(16) ushort lds[24832];
  const int QOFF = 0;
  const int KOFF = 8192;
  const int VOFF = 8192 + 8320;

  const int tid = threadIdx.x;
  const int mb = blockIdx.x & 63;
  const int h  = blockIdx.x >> 6;
  const int rb = mb * 128;
  const int b  = rb >> 10;
  const int n0 = rb & 1023;
  const int RS = 3 * C_DIM;

#pragma unroll
  for (int i = 0; i < 4; ++i) {
    int s = i * 256 + tid;
    int r = s >> 3;
    int jg = (s & 7) ^ (r & 7);
    gload_lds16(qkv + (size_t)(rb + r) * RS + h * HD + jg * 8,
                lds + QOFF + s * 8);
  }
#pragma unroll
  for (int i = 0; i < 5; ++i) {
    int s = i * 256 + tid;
    if (s < 1040) {
      int r = s >> 3;
      int jg = (s & 7) ^ (r & 7);
      int nl = n0 + r - 1;
      nl = nl < 0 ? 0 : (nl > 1023 ? 1023 : nl);
      size_t row = (size_t)(b << 10) + nl;
      gload_lds16(qkv + row * RS + C_DIM + h * HD + jg * 8, lds + KOFF + s * 8);
      gload_lds16(qkv + row * RS + 2 * C_DIM + h * HD + jg * 8, lds + VOFF + s * 8);
    }
  }
  __syncthreads();

  const int r = tid >> 1;
  const int half = tid & 1;
  const int jbase = half * 4;
  const int n = n0 + r;

  float qf[32];
#pragma unroll
  for (int c = 0; c < 4; ++c) {
    int slot = r * 8 + ((jbase + c) ^ (r & 7));
    s16x8 v = *(const s16x8*)(lds + QOFF + slot * 8);
#pragma unroll
    for (int e = 0; e < 8; ++e) qf[c * 8 + e] = bf2f(v[e]);
  }

  float s3[3];
#pragma unroll
  for (int jj = 0; jj < 3; ++jj) {
    int krow = r + jj;
    float acc = 0.f;
#pragma unroll
    for (int c = 0; c < 4; ++c) {
      int slot = krow * 8 + ((jbase + c) ^ (krow & 7));
      s16x8 v = *(const s16x8*)(lds + KOFF + slot * 8);
#pragma unroll
      for (int e = 0; e < 8; ++e) acc += qf[c * 8 + e] * bf2f(v[e]);
    }
    acc += __shfl_xor(acc, 1);
    s3[jj] = ((unsigned)(n + jj - 1) < (unsigned)NSEQ) ? acc * 0.125f : -1e30f;
  }

  float mx = fmaxf(s3[0], fmaxf(s3[1], s3[2]));
  float p0 = __expf(s3[0] - mx);
  float p1 = __expf(s3[1] - mx);
  float p2 = __expf(s3[2] - mx);
  float inv = 1.f / (p0 + p1 + p2);
  float p[3] = {p0 * inv, p1 * inv, p2 * inv};

  float of[32] = {};
#pragma unroll
  for (int jj = 0; jj < 3; ++jj) {
    int krow = r + jj;
    float pw = p[jj];
#pragma unroll
    for (int c = 0; c < 4; ++c) {
      int slot = krow * 8 + ((jbase + c) ^ (krow & 7));
      s16x8 v = *(const s16x8*)(lds + VOFF + slot * 8);
#pragma unroll
      for (int e = 0; e < 8; ++e) of[c * 8 + e] += pw * bf2f(v[e]);
    }
  }

#pragma unroll
  for (int c = 0; c < 4; ++c) {
    s16x8 o;
#pragma unroll
    for (int e = 0; e < 8; ++e) o[e] = f2bf(of[c * 8 + e]);
    *(s16x8*)(attn_out + (size_t)(rb + r) * C_DIM + h * HD + jbase * 8 + c * 8) = o;
  }
}

extern "C" void kernel_launch(void* const* d_in, const int* in_sizes, int n_in,
                              void* d_out, int out_size, void* d_ws, size_t ws_size,
                              hipStream_t stream) {
  const float* x      = (const float*)d_in[0];  // [B,N,C]
  const float* qkv_w  = (const float*)d_in[1];  // [3C,C]
  const float* proj_w = (const float*)d_in[2];  // [C,C]
  const float* proj_b = (const float*)d_in[3];  // [C]
  float* out = (float*)d_out;                   // [B,N,C] fp32

  __hip_bfloat16* qkv_bf  = (__hip_bfloat16*)d_ws;                 // [8192,1152]
  __hip_bfloat16* attn_bf = qkv_bf + (size_t)M_ROWS * 3 * C_DIM;   // [8192,384]

  // 1) qkv = x @ qkv_w^T (fused fp32->bf16 cast), 18x64 = 1152 blocks (~4.5/CU)
  gemm_rs<false, true><<<dim3(18, 64), 256, 0, stream>>>(
      x, qkv_w, nullptr, qkv_bf, M_ROWS, 3 * C_DIM, C_DIM);

  // 2) banded local attention (window 3): 64 row-panels x 6 heads
  local_attn_v3<<<64 * NHEADS, 256, 0, stream>>>(qkv_bf, attn_bf);

  // 3) out = attn @ proj_w^T + proj_b, 6x64 = 384 blocks
  gemm_rs<true, false><<<dim3(6, 64), 256, 0, stream>>>(
      attn_bf, proj_w, proj_b, out, M_ROWS, C_DIM, C_DIM);
}